// Round 12
// baseline (191.315 us; speedup 1.0000x reference)
//
#include <hip/hip_runtime.h>
#include <cstdint>
#include <cstddef>

typedef unsigned short u16;
typedef __attribute__((ext_vector_type(2))) float f32x2;
typedef __attribute__((ext_vector_type(4))) float f32x4;
typedef __attribute__((ext_vector_type(8))) short bf16x8;

#define LN_EPS 1e-5f
#define WAITV(n) asm volatile("s_waitcnt vmcnt(" #n ")" ::: "memory")
#define LGKM0    asm volatile("s_waitcnt lgkmcnt(0)" ::: "memory")
#define BAR()    do { __builtin_amdgcn_s_barrier(); asm volatile("" ::: "memory"); } while (0)

__device__ __forceinline__ u16 f2bf(float f) {
  unsigned int u = __float_as_uint(f);
  u += 0x7FFFu + ((u >> 16) & 1u);
  return (u16)(u >> 16);
}

__device__ __forceinline__ float l0gate(float loga) {
  float s = 1.0f / (1.0f + expf(-loga));
  float v = s * 1.2f - 0.1f;   // sigmoid*(zeta-gamma)+gamma
  return fminf(fmaxf(v, 0.0f), 1.0f);
}

__device__ __forceinline__ void llds16(u16* lds, const u16* g) {
  __builtin_amdgcn_global_load_lds(
      (const __attribute__((address_space(1))) unsigned int*)g,
      (__attribute__((address_space(3))) unsigned int*)lds, 16, 0, 0);
}

// ---- prep: fold L0 gate into bf16 weights ----
__global__ __launch_bounds__(256) void prep_weights(
    const float* __restrict__ dw, const float* __restrict__ uw,
    const float* __restrict__ dloga, const float* __restrict__ uloga,
    const int* __restrict__ lang,
    u16* __restrict__ dwb, u16* __restrict__ uwb) {
  const int lid = lang[0];
  const unsigned i = blockIdx.x * 256u + threadIdx.x;
  dwb[i] = f2bf(dw[i] * l0gate(dloga[lid * 2048 + (i & 2047u)]));
  uwb[i] = f2bf(uw[i] * l0gate(uloga[lid * 512 + (i & 511u)]));
}

// ---- LayerNorm over D=2048 + bf16 cast; one block per token row ----
__global__ __launch_bounds__(256) void ln_kernel(
    const float* __restrict__ x, const float* __restrict__ g,
    const float* __restrict__ b, u16* __restrict__ h1) {
  const int row = blockIdx.x;
  const int tid = threadIdx.x;
  const float4* xr = (const float4*)(x + (size_t)row * 2048);
  float4 v0 = xr[tid * 2 + 0];
  float4 v1 = xr[tid * 2 + 1];
  float s = v0.x + v0.y + v0.z + v0.w + v1.x + v1.y + v1.z + v1.w;
  float q = v0.x * v0.x + v0.y * v0.y + v0.z * v0.z + v0.w * v0.w +
            v1.x * v1.x + v1.y * v1.y + v1.z * v1.z + v1.w * v1.w;
#pragma unroll
  for (int off = 32; off > 0; off >>= 1) {
    s += __shfl_down(s, off, 64);
    q += __shfl_down(q, off, 64);
  }
  __shared__ float ss[4], sq[4], sstat[2];
  const int wave = tid >> 6, lane = tid & 63;
  if (lane == 0) { ss[wave] = s; sq[wave] = q; }
  __syncthreads();
  if (tid == 0) {
    float S = ss[0] + ss[1] + ss[2] + ss[3];
    float Q = sq[0] + sq[1] + sq[2] + sq[3];
    float mu = S * (1.0f / 2048.0f);
    float var = Q * (1.0f / 2048.0f) - mu * mu;
    sstat[0] = mu;
    sstat[1] = rsqrtf(var + LN_EPS);
  }
  __syncthreads();
  const float mu = sstat[0], rs = sstat[1];
  const float4* g4 = (const float4*)g;
  const float4* b4 = (const float4*)b;
  float4 ga = g4[tid * 2], gb = g4[tid * 2 + 1];
  float4 ba = b4[tid * 2], bb = b4[tid * 2 + 1];
  union { u16 us[8]; uint4 u; } p;
  p.us[0] = f2bf((v0.x - mu) * rs * ga.x + ba.x);
  p.us[1] = f2bf((v0.y - mu) * rs * ga.y + ba.y);
  p.us[2] = f2bf((v0.z - mu) * rs * ga.z + ba.z);
  p.us[3] = f2bf((v0.w - mu) * rs * ga.w + ba.w);
  p.us[4] = f2bf((v1.x - mu) * rs * gb.x + bb.x);
  p.us[5] = f2bf((v1.y - mu) * rs * gb.y + bb.y);
  p.us[6] = f2bf((v1.z - mu) * rs * gb.z + bb.z);
  p.us[7] = f2bf((v1.w - mu) * rs * gb.w + bb.w);
  ((uint4*)(h1 + (size_t)row * 2048))[tid] = p.u;
}

// ---- gemm1: h2 = relu(h1 * dwb^T + down_b), bf16 out (R9 version, proven) ----
__global__ __launch_bounds__(256) void gemm1(
    const u16* __restrict__ A, const u16* __restrict__ Bw,
    int M, int K, int NX,
    const float* __restrict__ bias,
    u16* __restrict__ outp) {
  const int N = 512;
  __shared__ __align__(16) char smem[65536];
  u16* As = (u16*)smem;
  u16* Bs = (u16*)(smem + 32768);
  float* Cs = (float*)smem;

  const int tid = threadIdx.x;
  const int wave = tid >> 6, lane = tid & 63;
  const int wr = (wave >> 1) * 64, wc = (wave & 1) * 64;
  const int lrow = lane & 15, lk = lane >> 4;

  const int nwg = gridDim.x;
  const int wg = (blockIdx.x & 7) * (nwg >> 3) + (blockIdx.x >> 3);
  const int bx = wg % NX, by = wg / NX;
  const size_t m0 = (size_t)by * 128, n0 = (size_t)bx * 128;

  f32x4 acc[4][4] = {};

  const int srow = lane >> 3;
  const int sslot = ((lane & 7) ^ ((lane >> 3) & 7)) * 8;
  auto STAGE = [&](int buf, int k0) {
#pragma unroll
    for (int c = 0; c < 4; ++c) {
      const int seg = c * 4 + wave;
      const int r = seg * 8 + srow;
      llds16(As + buf * 8192 + seg * 512, A + (m0 + r) * (size_t)K + (k0 + sslot));
      llds16(Bs + buf * 8192 + seg * 512, Bw + (n0 + r) * (size_t)K + (k0 + sslot));
    }
  };

  const int NT = K >> 6;
  STAGE(0, 0);

  for (int t = 0; t < NT; ++t) {
    const int cur = t & 1;
    if (t + 1 < NT) {
      STAGE(cur ^ 1, (t + 1) << 6);
      WAITV(8);
    } else {
      WAITV(0);
    }
    BAR();

    const u16* Ab = As + cur * 8192;
    const u16* Bb = Bs + cur * 8192;
#pragma unroll
    for (int ks = 0; ks < 2; ++ks) {
      bf16x8 af[4], bfr[4];
#pragma unroll
      for (int m = 0; m < 4; ++m)
        af[m] = *(const bf16x8*)&Ab[(wr + m * 16 + lrow) * 64 +
                                    ((unsigned)((ks * 4 + lk) ^ (lane & 7))) * 8];
#pragma unroll
      for (int n = 0; n < 4; ++n)
        bfr[n] = *(const bf16x8*)&Bb[(wc + n * 16 + lrow) * 64 +
                                     ((unsigned)((ks * 4 + lk) ^ (lane & 7))) * 8];
      __builtin_amdgcn_s_setprio(1);
#pragma unroll
      for (int m = 0; m < 4; ++m)
#pragma unroll
        for (int n = 0; n < 4; ++n)
          acc[m][n] = __builtin_amdgcn_mfma_f32_16x16x32_bf16(af[m], bfr[n],
                                                              acc[m][n], 0, 0, 0);
      __builtin_amdgcn_s_setprio(0);
    }
    LGKM0;
    BAR();
  }

#pragma unroll
  for (int n = 0; n < 4; ++n) {
    const int c = wc + n * 16 + lrow;
    const float bv = bias[n0 + c];
#pragma unroll
    for (int m = 0; m < 4; ++m) {
#pragma unroll
      for (int r = 0; r < 4; ++r) {
        const int row = wr + m * 16 + lk * 4 + r;
        Cs[row * 128 + ((c + ((row >> 2) << 3)) & 127)] = acc[m][n][r] + bv;
      }
    }
  }
  LGKM0;
  BAR();

#pragma unroll
  for (int j = 0; j < 8; ++j) {
    const int flat = tid * 8 + j * 2048;
    const int row = flat >> 7, c = flat & 127;
    const int cp = (c + ((row >> 2) << 3)) & 127;
    const f32x4 c0 = *(const f32x4*)&Cs[row * 128 + cp];
    const f32x4 c1 = *(const f32x4*)&Cs[row * 128 + cp + 4];
    union { u16 us[8]; uint4 u; } p;
    p.us[0] = f2bf(fmaxf(c0[0], 0.0f)); p.us[1] = f2bf(fmaxf(c0[1], 0.0f));
    p.us[2] = f2bf(fmaxf(c0[2], 0.0f)); p.us[3] = f2bf(fmaxf(c0[3], 0.0f));
    p.us[4] = f2bf(fmaxf(c1[0], 0.0f)); p.us[5] = f2bf(fmaxf(c1[1], 0.0f));
    p.us[6] = f2bf(fmaxf(c1[2], 0.0f)); p.us[7] = f2bf(fmaxf(c1[3], 0.0f));
    *(uint4*)&outp[(m0 + row) * (size_t)N + n0 + c] = p.u;
  }
}

// ---- gemm2p: persistent paced GEMM. out = h2*uwb^T + up_b + x.
// 1024 blocks; each: n-panel of 64 cols (bx), 4 M-tiles of 128 rows.
// Tile 128x64, BK=32, NT=16, dbuf, R7 4-slot swizzle. Cs (32KB) disjoint from
// staging (24KB) -> prev tile's output lives in Cs through the next K-loop;
// its stores + resid-x loads are PACED 1/iter into the counted vmcnt schedule
// (vmcnt retires in issue order, m135). No burst prologue/epilogue.
__global__ __launch_bounds__(256) void gemm2p(
    const u16* __restrict__ A, const u16* __restrict__ Bw,
    const float* __restrict__ bias_g, const float* __restrict__ X,
    float* __restrict__ outp) {
  __shared__ __align__(16) char smem[57344];
  u16* As = (u16*)smem;                  // [2][128*32] bf16 : 16 KB
  u16* Bs = (u16*)(smem + 16384);        // [2][64*32]  bf16 :  8 KB
  float* Cs = (float*)(smem + 24576);    // [128][64] f32    : 32 KB

  const int tid = threadIdx.x;
  const int wave = tid >> 6, lane = tid & 63;
  const int wr = (wave >> 1) * 64;       // wave rows: 0 or 64
  const int wcc = (wave & 1) * 32;       // wave cols: 0 or 32
  const int lrow = lane & 15, lk = lane >> 4;

  const int nwg = gridDim.x;             // 1024, %8==0
  const int wg = (blockIdx.x & 7) * (nwg >> 3) + (blockIdx.x >> 3);
  const int bx = wg & 31;                // 32 n-panels
  const int bys = wg >> 5;               // 32 M-supertiles (4 tiles each)
  const size_t n0 = (size_t)bx * 64;
  const size_t mbase = (size_t)bys * 512;

  // staging maps (R7-proven 4-slot both-sides swizzle)
  const int crow = lane >> 2;                              // 16 rows/chunk
  const int ckk = ((lane & 3) ^ ((lane >> 3) & 3)) * 8;    // pre-swizzled src slot
  const int pos8 = ((unsigned)(lk ^ ((lrow >> 1) & 3))) * 8;  // swizzled read

  // 2 bias values (issued first -> oldest vmem, retired by first wait)
  const float bias0 = bias_g[n0 + wcc + lrow];
  const float bias1 = bias_g[n0 + wcc + 16 + lrow];

  // stage one K-subtile (3 llds16 per wave: 2 A-chunks + 1 B-chunk)
  auto STAGE = [&](int buf, size_t m0, int k0) {
    llds16(As + buf * 4096 + (wave * 2 + 0) * 512,
           A + (m0 + (wave * 2 + 0) * 16 + crow) * 512 + k0 + ckk);
    llds16(As + buf * 4096 + (wave * 2 + 1) * 512,
           A + (m0 + (wave * 2 + 1) * 16 + crow) * 512 + k0 + ckk);
    llds16(Bs + buf * 2048 + wave * 512,
           Bw + (n0 + wave * 16 + crow) * 512 + k0 + ckk);
  };

  // slice geometry for paced resid/stores: slice s = 8 rows (256 thr x f32x2)
  // flat = tid*2 + s*512 ; row = flat>>6 ; col = flat&63 (even, pair-safe)
  const int srow_ = (tid * 2) >> 6;       // row offset within slice base 8*s
  const int scol_ = (tid * 2) & 63;
  const int scp_ = (scol_ + (((srow_ /*+8s*/) >> 2) << 3)) & 63;  // rot depends on row>>2; 8s ≡ 0 mod 4 in row>>2 shift? (8s)>>2 = 2s -> changes!
  // NOTE: rot must use full row = srow_ + 8*s; computed per slice below.

  STAGE(0, mbase, 0);                     // first prologue (3)

  for (int it = 0; it < 4; ++it) {
    const size_t m0 = mbase + (size_t)it * 128;
    const size_t m0p = m0 - 128;          // prev tile (valid when it>0)
    f32x4 acc[4][2] = {};
    f32x2 xpv[16];

#pragma unroll
    for (int t = 0; t < 16; ++t) {
      // ---- pre-wait issues ----
      if (t < 15) STAGE((t + 1) & 1, m0, (t + 1) * 32);
      if (it > 0) {
        if (t == 0) {
#pragma unroll
          for (int s = 0; s < 3; ++s) {
            const int row = ((tid * 2 + s * 512) >> 6);
            xpv[s] = *(const f32x2*)&X[(m0p + row) * 2048 + n0 + scol_];
          }
        } else if (t <= 13) {
          const int s = t + 2;
          const int row = ((tid * 2 + s * 512) >> 6);
          xpv[s] = *(const f32x2*)&X[(m0p + row) * 2048 + n0 + scol_];
        }
      }
      // ---- counted wait (derived; see schedule comment) ----
      if (it == 0) {
        if (t < 15) WAITV(3); else WAITV(0);
      } else {
        if (t <= 13) WAITV(6);
        else if (t == 14) WAITV(5);
        else WAITV(1);
      }
      // ---- post-wait: paced store of prev tile slice t-1 ----
      if (it > 0 && t >= 1) {
        const int s = t - 1;
        const int row = ((tid * 2 + s * 512) >> 6);
        const int cp = (scol_ + ((row >> 2) << 3)) & 63;
        const f32x2 cv = *(const f32x2*)&Cs[row * 64 + cp];
        f32x2 o; o[0] = cv[0] + xpv[s][0]; o[1] = cv[1] + xpv[s][1];
        *(f32x2*)&outp[(m0p + row) * 2048 + n0 + scol_] = o;
      }
      BAR();
      // ---- compute ----
      const u16* Ab = As + (t & 1) * 4096;
      const u16* Bb = Bs + (t & 1) * 2048;
      bf16x8 af[4], bfr[2];
#pragma unroll
      for (int m = 0; m < 4; ++m)
        af[m] = *(const bf16x8*)&Ab[(wr + m * 16 + lrow) * 32 + pos8];
#pragma unroll
      for (int n = 0; n < 2; ++n)
        bfr[n] = *(const bf16x8*)&Bb[(wcc + n * 16 + lrow) * 32 + pos8];
      __builtin_amdgcn_s_setprio(1);
#pragma unroll
      for (int m = 0; m < 4; ++m)
#pragma unroll
        for (int n = 0; n < 2; ++n)
          acc[m][n] = __builtin_amdgcn_mfma_f32_16x16x32_bf16(af[m], bfr[n],
                                                              acc[m][n], 0, 0, 0);
      __builtin_amdgcn_s_setprio(0);
      LGKM0;
      BAR();
    }

    // ---- epilogue ----
    if (it > 0) {               // last slice (15) of prev tile
      const int s = 15;
      const int row = ((tid * 2 + s * 512) >> 6);
      const int cp = (scol_ + ((row >> 2) << 3)) & 63;
      const f32x2 cv = *(const f32x2*)&Cs[row * 64 + cp];
      f32x2 o; o[0] = cv[0] + xpv[s][0]; o[1] = cv[1] + xpv[s][1];
      *(f32x2*)&outp[(m0p + row) * 2048 + n0 + scol_] = o;
      LGKM0;                    // my Cs read done before overwrite
    }
    BAR();                      // all waves' Cs reads done
    if (it < 3) STAGE(0, m0 + 128, 0);   // next tile prologue (3, buf0 free)

    // acc(+bias) -> Cs (all waves, disjoint rows/cols), stays for next K-loop
#pragma unroll
    for (int n = 0; n < 2; ++n) {
      const int c = wcc + n * 16 + lrow;
      const float bv = (n == 0) ? bias0 : bias1;
#pragma unroll
      for (int m = 0; m < 4; ++m) {
#pragma unroll
        for (int r = 0; r < 4; ++r) {
          const int row = wr + m * 16 + lk * 4 + r;
          Cs[row * 64 + ((c + ((row >> 2) << 3)) & 63)] = acc[m][n][r] + bv;
        }
      }
    }
    LGKM0;                      // writes visible before next loop's barrier
  }

  // ---- final drain: tile 3's output (no next K-loop to pace into) ----
  BAR();                        // Cs writes of tile 3 visible to all
  f32x2 xf[16];
#pragma unroll
  for (int s = 0; s < 16; ++s) {
    const int row = ((tid * 2 + s * 512) >> 6);
    xf[s] = *(const f32x2*)&X[(mbase + 384 + row) * 2048 + n0 + scol_];
  }
  WAITV(0);
#pragma unroll
  for (int s = 0; s < 16; ++s) {
    const int row = ((tid * 2 + s * 512) >> 6);
    const int cp = (scol_ + ((row >> 2) << 3)) & 63;
    const f32x2 cv = *(const f32x2*)&Cs[row * 64 + cp];
    f32x2 o; o[0] = cv[0] + xf[s][0]; o[1] = cv[1] + xf[s][1];
    *(f32x2*)&outp[(mbase + 384 + row) * 2048 + n0 + scol_] = o;
  }
}

extern "C" void kernel_launch(void* const* d_in, const int* in_sizes, int n_in,
                              void* d_out, int out_size, void* d_ws, size_t ws_size,
                              hipStream_t stream) {
  const float* x         = (const float*)d_in[0];
  const float* down_w    = (const float*)d_in[1];
  const float* down_b    = (const float*)d_in[2];
  const float* up_w      = (const float*)d_in[3];
  const float* up_b      = (const float*)d_in[4];
  const float* ln_g      = (const float*)d_in[5];
  const float* ln_b      = (const float*)d_in[6];
  const float* down_loga = (const float*)d_in[7];
  const float* up_loga   = (const float*)d_in[8];
  const int*   lang      = (const int*)d_in[9];

  const int D = 2048, BNK = 512;
  const int M = in_sizes[0] / D;  // 16384

  char* ws = (char*)d_ws;
  u16* h1  = (u16*)ws;                                   // [M][D] bf16
  u16* h2  = (u16*)(ws + (size_t)M * D * 2);             // [M][BNK] bf16
  u16* dwb = (u16*)(ws + (size_t)M * D * 2 + (size_t)M * BNK * 2);  // [BNK][D]
  u16* uwb = dwb + (size_t)BNK * D;                      // [D][BNK]

  prep_weights<<<(BNK * D) / 256, 256, 0, stream>>>(down_w, up_w, down_loga,
                                                    up_loga, lang, dwb, uwb);
  ln_kernel<<<M, 256, 0, stream>>>(x, ln_g, ln_b, h1);
  gemm1<<<(M / 128) * (BNK / 128), 256, 0, stream>>>(h1, dwb, M, D, BNK / 128,
                                                     down_b, h2);
  gemm2p<<<(M / 128 / 4) * (D / 64), 256, 0, stream>>>(h2, uwb, up_b, x,
                                                       (float*)d_out);
}

// Round 13
// 162.142 us; speedup vs baseline: 1.1799x; 1.1799x over previous
//
#include <hip/hip_runtime.h>
#include <cstdint>
#include <cstddef>

typedef unsigned short u16;
typedef __attribute__((ext_vector_type(4))) float f32x4;
typedef __attribute__((ext_vector_type(8))) short bf16x8;

#define LN_EPS 1e-5f
#define WAITV(n) asm volatile("s_waitcnt vmcnt(" #n ")" ::: "memory")
#define LGKM0    asm volatile("s_waitcnt lgkmcnt(0)" ::: "memory")
#define BAR()    do { __builtin_amdgcn_s_barrier(); asm volatile("" ::: "memory"); } while (0)

__device__ __forceinline__ u16 f2bf(float f) {
  unsigned int u = __float_as_uint(f);
  u += 0x7FFFu + ((u >> 16) & 1u);
  return (u16)(u >> 16);
}

__device__ __forceinline__ float l0gate(float loga) {
  float s = 1.0f / (1.0f + expf(-loga));
  float v = s * 1.2f - 0.1f;   // sigmoid*(zeta-gamma)+gamma
  return fminf(fmaxf(v, 0.0f), 1.0f);
}

__device__ __forceinline__ void llds16(u16* lds, const u16* g) {
  __builtin_amdgcn_global_load_lds(
      (const __attribute__((address_space(1))) unsigned int*)g,
      (__attribute__((address_space(3))) unsigned int*)lds, 16, 0, 0);
}

// ---- prep: fold L0 gate into bf16 weights ----
__global__ __launch_bounds__(256) void prep_weights(
    const float* __restrict__ dw, const float* __restrict__ uw,
    const float* __restrict__ dloga, const float* __restrict__ uloga,
    const int* __restrict__ lang,
    u16* __restrict__ dwb, u16* __restrict__ uwb) {
  const int lid = lang[0];
  const unsigned i = blockIdx.x * 256u + threadIdx.x;
  dwb[i] = f2bf(dw[i] * l0gate(dloga[lid * 2048 + (i & 2047u)]));
  uwb[i] = f2bf(uw[i] * l0gate(uloga[lid * 512 + (i & 511u)]));
}

// ---- LayerNorm over D=2048 + bf16 cast; one block per token row ----
__global__ __launch_bounds__(256) void ln_kernel(
    const float* __restrict__ x, const float* __restrict__ g,
    const float* __restrict__ b, u16* __restrict__ h1) {
  const int row = blockIdx.x;
  const int tid = threadIdx.x;
  const float4* xr = (const float4*)(x + (size_t)row * 2048);
  float4 v0 = xr[tid * 2 + 0];
  float4 v1 = xr[tid * 2 + 1];
  float s = v0.x + v0.y + v0.z + v0.w + v1.x + v1.y + v1.z + v1.w;
  float q = v0.x * v0.x + v0.y * v0.y + v0.z * v0.z + v0.w * v0.w +
            v1.x * v1.x + v1.y * v1.y + v1.z * v1.z + v1.w * v1.w;
#pragma unroll
  for (int off = 32; off > 0; off >>= 1) {
    s += __shfl_down(s, off, 64);
    q += __shfl_down(q, off, 64);
  }
  __shared__ float ss[4], sq[4], sstat[2];
  const int wave = tid >> 6, lane = tid & 63;
  if (lane == 0) { ss[wave] = s; sq[wave] = q; }
  __syncthreads();
  if (tid == 0) {
    float S = ss[0] + ss[1] + ss[2] + ss[3];
    float Q = sq[0] + sq[1] + sq[2] + sq[3];
    float mu = S * (1.0f / 2048.0f);
    float var = Q * (1.0f / 2048.0f) - mu * mu;
    sstat[0] = mu;
    sstat[1] = rsqrtf(var + LN_EPS);
  }
  __syncthreads();
  const float mu = sstat[0], rs = sstat[1];
  const float4* g4 = (const float4*)g;
  const float4* b4 = (const float4*)b;
  float4 ga = g4[tid * 2], gb = g4[tid * 2 + 1];
  float4 ba = b4[tid * 2], bb = b4[tid * 2 + 1];
  union { u16 us[8]; uint4 u; } p;
  p.us[0] = f2bf((v0.x - mu) * rs * ga.x + ba.x);
  p.us[1] = f2bf((v0.y - mu) * rs * ga.y + ba.y);
  p.us[2] = f2bf((v0.z - mu) * rs * ga.z + ba.z);
  p.us[3] = f2bf((v0.w - mu) * rs * ga.w + ba.w);
  p.us[4] = f2bf((v1.x - mu) * rs * gb.x + bb.x);
  p.us[5] = f2bf((v1.y - mu) * rs * gb.y + bb.y);
  p.us[6] = f2bf((v1.z - mu) * rs * gb.z + bb.z);
  p.us[7] = f2bf((v1.w - mu) * rs * gb.w + bb.w);
  ((uint4*)(h1 + (size_t)row * 2048))[tid] = p.u;
}

// ---- gemm1: h2 = relu(h1 * dwb^T + down_b), bf16 out (R9 version, proven) ----
__global__ __launch_bounds__(256) void gemm1(
    const u16* __restrict__ A, const u16* __restrict__ Bw,
    int M, int K, int NX,
    const float* __restrict__ bias,
    u16* __restrict__ outp) {
  const int N = 512;
  __shared__ __align__(16) char smem[65536];
  u16* As = (u16*)smem;
  u16* Bs = (u16*)(smem + 32768);
  float* Cs = (float*)smem;

  const int tid = threadIdx.x;
  const int wave = tid >> 6, lane = tid & 63;
  const int wr = (wave >> 1) * 64, wc = (wave & 1) * 64;
  const int lrow = lane & 15, lk = lane >> 4;

  const int nwg = gridDim.x;
  const int wg = (blockIdx.x & 7) * (nwg >> 3) + (blockIdx.x >> 3);
  const int bx = wg % NX, by = wg / NX;
  const size_t m0 = (size_t)by * 128, n0 = (size_t)bx * 128;

  f32x4 acc[4][4] = {};

  const int srow = lane >> 3;
  const int sslot = ((lane & 7) ^ ((lane >> 3) & 7)) * 8;
  auto STAGE = [&](int buf, int k0) {
#pragma unroll
    for (int c = 0; c < 4; ++c) {
      const int seg = c * 4 + wave;
      const int r = seg * 8 + srow;
      llds16(As + buf * 8192 + seg * 512, A + (m0 + r) * (size_t)K + (k0 + sslot));
      llds16(Bs + buf * 8192 + seg * 512, Bw + (n0 + r) * (size_t)K + (k0 + sslot));
    }
  };

  const int NT = K >> 6;
  STAGE(0, 0);

  for (int t = 0; t < NT; ++t) {
    const int cur = t & 1;
    if (t + 1 < NT) {
      STAGE(cur ^ 1, (t + 1) << 6);
      WAITV(8);
    } else {
      WAITV(0);
    }
    BAR();

    const u16* Ab = As + cur * 8192;
    const u16* Bb = Bs + cur * 8192;
#pragma unroll
    for (int ks = 0; ks < 2; ++ks) {
      bf16x8 af[4], bfr[4];
#pragma unroll
      for (int m = 0; m < 4; ++m)
        af[m] = *(const bf16x8*)&Ab[(wr + m * 16 + lrow) * 64 +
                                    ((unsigned)((ks * 4 + lk) ^ (lane & 7))) * 8];
#pragma unroll
      for (int n = 0; n < 4; ++n)
        bfr[n] = *(const bf16x8*)&Bb[(wc + n * 16 + lrow) * 64 +
                                     ((unsigned)((ks * 4 + lk) ^ (lane & 7))) * 8];
      __builtin_amdgcn_s_setprio(1);
#pragma unroll
      for (int m = 0; m < 4; ++m)
#pragma unroll
        for (int n = 0; n < 4; ++n)
          acc[m][n] = __builtin_amdgcn_mfma_f32_16x16x32_bf16(af[m], bfr[n],
                                                              acc[m][n], 0, 0, 0);
      __builtin_amdgcn_s_setprio(0);
    }
    LGKM0;
    BAR();
  }

#pragma unroll
  for (int n = 0; n < 4; ++n) {
    const int c = wc + n * 16 + lrow;
    const float bv = bias[n0 + c];
#pragma unroll
    for (int m = 0; m < 4; ++m) {
#pragma unroll
      for (int r = 0; r < 4; ++r) {
        const int row = wr + m * 16 + lk * 4 + r;
        Cs[row * 128 + ((c + ((row >> 2) << 3)) & 127)] = acc[m][n][r] + bv;
      }
    }
  }
  LGKM0;
  BAR();

#pragma unroll
  for (int j = 0; j < 8; ++j) {
    const int flat = tid * 8 + j * 2048;
    const int row = flat >> 7, c = flat & 127;
    const int cp = (c + ((row >> 2) << 3)) & 127;
    const f32x4 c0 = *(const f32x4*)&Cs[row * 128 + cp];
    const f32x4 c1 = *(const f32x4*)&Cs[row * 128 + cp + 4];
    union { u16 us[8]; uint4 u; } p;
    p.us[0] = f2bf(fmaxf(c0[0], 0.0f)); p.us[1] = f2bf(fmaxf(c0[1], 0.0f));
    p.us[2] = f2bf(fmaxf(c0[2], 0.0f)); p.us[3] = f2bf(fmaxf(c0[3], 0.0f));
    p.us[4] = f2bf(fmaxf(c1[0], 0.0f)); p.us[5] = f2bf(fmaxf(c1[1], 0.0f));
    p.us[6] = f2bf(fmaxf(c1[2], 0.0f)); p.us[7] = f2bf(fmaxf(c1[3], 0.0f));
    *(uint4*)&outp[(m0 + row) * (size_t)N + n0 + c] = p.u;
  }
}

// ---- gemm2: out = h2*uwb^T + up_b + resid; K=512 fixed, fully unrolled.
// Resid loads spread into the K-loop (counted into vmcnt). (R9 version, proven.)
__global__ __launch_bounds__(256) void gemm2(
    const u16* __restrict__ A, const u16* __restrict__ Bw,
    int M, const float* __restrict__ bias,
    const float* __restrict__ resid, float* __restrict__ outp) {
  const int K = 512, N = 2048;
  __shared__ __align__(16) char smem[65536];
  u16* As = (u16*)smem;
  u16* Bs = (u16*)(smem + 32768);
  float* Cs = (float*)smem;

  const int tid = threadIdx.x;
  const int wave = tid >> 6, lane = tid & 63;
  const int wr = (wave >> 1) * 64, wc = (wave & 1) * 64;
  const int lrow = lane & 15, lk = lane >> 4;

  const int nwg = gridDim.x;            // %8==0
  const int wg = (blockIdx.x & 7) * (nwg >> 3) + (blockIdx.x >> 3);
  const int bx = wg & 15, by = wg >> 4; // NX=16
  const size_t m0 = (size_t)by * 128, n0 = (size_t)bx * 128;

  f32x4 acc[4][4] = {};

  const int srow = lane >> 3;
  const int sslot = ((lane & 7) ^ ((lane >> 3) & 7)) * 8;
  auto STAGE = [&](int buf, int k0) {
#pragma unroll
    for (int c = 0; c < 4; ++c) {
      const int seg = c * 4 + wave;
      const int r = seg * 8 + srow;
      llds16(As + buf * 8192 + seg * 512, A + (m0 + r) * (size_t)K + (k0 + sslot));
      llds16(Bs + buf * 8192 + seg * 512, Bw + (n0 + r) * (size_t)K + (k0 + sslot));
    }
  };

  f32x4 rsd[16];
  auto RSD = [&](int j) {
    const int flat = tid * 4 + j * 1024;
    const int row = flat >> 7, c = flat & 127;
    rsd[j] = *(const f32x4*)&resid[(m0 + row) * (size_t)N + n0 + c];
  };

  STAGE(0, 0);                                    // 8 in flight
#pragma unroll
  for (int t = 0; t < 8; ++t) {
    const int cur = t & 1;
    if (t < 7) {
      STAGE(cur ^ 1, (t + 1) * 64);               // +8
      RSD(2 * t); RSD(2 * t + 1);                 // +2
      WAITV(10);                                  // tile t landed
    } else {
      RSD(14); RSD(15);
      WAITV(4);                                   // STAGE(7) landed
    }
    BAR();

    const u16* Ab = As + cur * 8192;
    const u16* Bb = Bs + cur * 8192;
#pragma unroll
    for (int ks = 0; ks < 2; ++ks) {
      bf16x8 af[4], bfr[4];
#pragma unroll
      for (int m = 0; m < 4; ++m)
        af[m] = *(const bf16x8*)&Ab[(wr + m * 16 + lrow) * 64 +
                                    ((unsigned)((ks * 4 + lk) ^ (lane & 7))) * 8];
#pragma unroll
      for (int n = 0; n < 4; ++n)
        bfr[n] = *(const bf16x8*)&Bb[(wc + n * 16 + lrow) * 64 +
                                     ((unsigned)((ks * 4 + lk) ^ (lane & 7))) * 8];
      __builtin_amdgcn_s_setprio(1);
#pragma unroll
      for (int m = 0; m < 4; ++m)
#pragma unroll
        for (int n = 0; n < 4; ++n)
          acc[m][n] = __builtin_amdgcn_mfma_f32_16x16x32_bf16(af[m], bfr[n],
                                                              acc[m][n], 0, 0, 0);
      __builtin_amdgcn_s_setprio(0);
    }
    LGKM0;
    BAR();
  }

  // epilogue: bias into Cs (rotated), transpose-read, add resid, f32 store
#pragma unroll
  for (int n = 0; n < 4; ++n) {
    const int c = wc + n * 16 + lrow;
    const float bv = bias[n0 + c];
#pragma unroll
    for (int m = 0; m < 4; ++m) {
#pragma unroll
      for (int r = 0; r < 4; ++r) {
        const int row = wr + m * 16 + lk * 4 + r;
        Cs[row * 128 + ((c + ((row >> 2) << 3)) & 127)] = acc[m][n][r] + bv;
      }
    }
  }
  LGKM0;
  BAR();

#pragma unroll
  for (int j = 0; j < 16; ++j) {
    const int flat = tid * 4 + j * 1024;
    const int row = flat >> 7, c = flat & 127;
    const f32x4 cc = *(const f32x4*)&Cs[row * 128 + ((c + ((row >> 2) << 3)) & 127)];
    f32x4 o;
    o[0] = cc[0] + rsd[j][0]; o[1] = cc[1] + rsd[j][1];
    o[2] = cc[2] + rsd[j][2]; o[3] = cc[3] + rsd[j][3];
    *(f32x4*)&outp[(m0 + row) * (size_t)N + n0 + c] = o;
  }
}

extern "C" void kernel_launch(void* const* d_in, const int* in_sizes, int n_in,
                              void* d_out, int out_size, void* d_ws, size_t ws_size,
                              hipStream_t stream) {
  const float* x         = (const float*)d_in[0];
  const float* down_w    = (const float*)d_in[1];
  const float* down_b    = (const float*)d_in[2];
  const float* up_w      = (const float*)d_in[3];
  const float* up_b      = (const float*)d_in[4];
  const float* ln_g      = (const float*)d_in[5];
  const float* ln_b      = (const float*)d_in[6];
  const float* down_loga = (const float*)d_in[7];
  const float* up_loga   = (const float*)d_in[8];
  const int*   lang      = (const int*)d_in[9];

  const int D = 2048, BNK = 512;
  const int M = in_sizes[0] / D;  // 16384
  const int MC = 8192;            // chunk rows: working set ~141 MB < 256 MB L3

  char* ws = (char*)d_ws;
  u16* h1  = (u16*)ws;                                   // [M][D] bf16
  u16* h2  = (u16*)(ws + (size_t)M * D * 2);             // [M][BNK] bf16
  u16* dwb = (u16*)(ws + (size_t)M * D * 2 + (size_t)M * BNK * 2);  // [BNK][D]
  u16* uwb = dwb + (size_t)BNK * D;                      // [D][BNK]

  prep_weights<<<(BNK * D) / 256, 256, 0, stream>>>(down_w, up_w, down_loga,
                                                    up_loga, lang, dwb, uwb);

  // chunked pipeline: per 8192-row chunk, ln -> gemm1 -> gemm2 so gemm2's
  // x-resid read hits L3 (x streamed by ln ~2 small dispatches earlier).
  for (int c = 0; c < M / MC; ++c) {
    const size_t ro = (size_t)c * MC;
    ln_kernel<<<MC, 256, 0, stream>>>(x + ro * D, ln_g, ln_b, h1 + ro * D);
    gemm1<<<(MC / 128) * (BNK / 128), 256, 0, stream>>>(
        h1 + ro * D, dwb, MC, D, BNK / 128, down_b, h2 + ro * BNK);
    gemm2<<<(MC / 128) * (D / 128), 256, 0, stream>>>(
        h2 + ro * BNK, uwb, MC, up_b, x + ro * D, (float*)d_out + ro * D);
  }
}

// Round 15
// 148.425 us; speedup vs baseline: 1.2890x; 1.0924x over previous
//
#include <hip/hip_runtime.h>
#include <cstdint>
#include <cstddef>

typedef unsigned short u16;
typedef __attribute__((ext_vector_type(4))) float f32x4;
typedef __attribute__((ext_vector_type(8))) short bf16x8;

#define LN_EPS 1e-5f
#define WAITV(n) asm volatile("s_waitcnt vmcnt(" #n ")" ::: "memory")
#define LGKM0    asm volatile("s_waitcnt lgkmcnt(0)" ::: "memory")
#define BAR()    do { __builtin_amdgcn_s_barrier(); asm volatile("" ::: "memory"); } while (0)

__device__ __forceinline__ u16 f2bf(float f) {
  unsigned int u = __float_as_uint(f);
  u += 0x7FFFu + ((u >> 16) & 1u);
  return (u16)(u >> 16);
}

__device__ __forceinline__ float l0gate(float loga) {
  float s = 1.0f / (1.0f + expf(-loga));
  float v = s * 1.2f - 0.1f;   // sigmoid*(zeta-gamma)+gamma
  return fminf(fmaxf(v, 0.0f), 1.0f);
}

__device__ __forceinline__ void llds16(u16* lds, const u16* g) {
  __builtin_amdgcn_global_load_lds(
      (const __attribute__((address_space(1))) unsigned int*)g,
      (__attribute__((address_space(3))) unsigned int*)lds, 16, 0, 0);
}

// ---- prep: fold L0 gate into bf16 weights ----
__global__ __launch_bounds__(256) void prep_weights(
    const float* __restrict__ dw, const float* __restrict__ uw,
    const float* __restrict__ dloga, const float* __restrict__ uloga,
    const int* __restrict__ lang,
    u16* __restrict__ dwb, u16* __restrict__ uwb) {
  const int lid = lang[0];
  const unsigned i = blockIdx.x * 256u + threadIdx.x;
  dwb[i] = f2bf(dw[i] * l0gate(dloga[lid * 2048 + (i & 2047u)]));
  uwb[i] = f2bf(uw[i] * l0gate(uloga[lid * 512 + (i & 511u)]));
}

// ---- LayerNorm over D=2048 + bf16 cast; one block per token row ----
__global__ __launch_bounds__(256) void ln_kernel(
    const float* __restrict__ x, const float* __restrict__ g,
    const float* __restrict__ b, u16* __restrict__ h1) {
  const int row = blockIdx.x;
  const int tid = threadIdx.x;
  const float4* xr = (const float4*)(x + (size_t)row * 2048);
  float4 v0 = xr[tid * 2 + 0];
  float4 v1 = xr[tid * 2 + 1];
  float s = v0.x + v0.y + v0.z + v0.w + v1.x + v1.y + v1.z + v1.w;
  float q = v0.x * v0.x + v0.y * v0.y + v0.z * v0.z + v0.w * v0.w +
            v1.x * v1.x + v1.y * v1.y + v1.z * v1.z + v1.w * v1.w;
#pragma unroll
  for (int off = 32; off > 0; off >>= 1) {
    s += __shfl_down(s, off, 64);
    q += __shfl_down(q, off, 64);
  }
  __shared__ float ss[4], sq[4], sstat[2];
  const int wave = tid >> 6, lane = tid & 63;
  if (lane == 0) { ss[wave] = s; sq[wave] = q; }
  __syncthreads();
  if (tid == 0) {
    float S = ss[0] + ss[1] + ss[2] + ss[3];
    float Q = sq[0] + sq[1] + sq[2] + sq[3];
    float mu = S * (1.0f / 2048.0f);
    float var = Q * (1.0f / 2048.0f) - mu * mu;
    sstat[0] = mu;
    sstat[1] = rsqrtf(var + LN_EPS);
  }
  __syncthreads();
  const float mu = sstat[0], rs = sstat[1];
  const float4* g4 = (const float4*)g;
  const float4* b4 = (const float4*)b;
  float4 ga = g4[tid * 2], gb = g4[tid * 2 + 1];
  float4 ba = b4[tid * 2], bb = b4[tid * 2 + 1];
  union { u16 us[8]; uint4 u; } p;
  p.us[0] = f2bf((v0.x - mu) * rs * ga.x + ba.x);
  p.us[1] = f2bf((v0.y - mu) * rs * ga.y + ba.y);
  p.us[2] = f2bf((v0.z - mu) * rs * ga.z + ba.z);
  p.us[3] = f2bf((v0.w - mu) * rs * ga.w + ba.w);
  p.us[4] = f2bf((v1.x - mu) * rs * gb.x + bb.x);
  p.us[5] = f2bf((v1.y - mu) * rs * gb.y + bb.y);
  p.us[6] = f2bf((v1.z - mu) * rs * gb.z + bb.z);
  p.us[7] = f2bf((v1.w - mu) * rs * gb.w + bb.w);
  ((uint4*)(h1 + (size_t)row * 2048))[tid] = p.u;
}

// ---- gemm1: h2 = relu(h1 * dwb^T + down_b), bf16 out ----
// 128x128 tile, BK=64. A (h1, long-latency cross-XCD) TRIPLE-buffered
// (depth-2 prefetch); B (weights, L2-resident) double-buffered.
// LDS: A 3x16KB @0, B 2x16KB @49152; Cs 64KB alias. 80 KB -> 2 blocks/CU.
// Per-iter issue order: SB_{t+1} BEFORE SA_{t+2} so retiring through SB_t
// never force-waits SA_{t+1} (in-order vmcnt retirement).
__global__ __launch_bounds__(256) void gemm1(
    const u16* __restrict__ A, const u16* __restrict__ Bw,
    int M, int K, int NX,
    const float* __restrict__ bias,
    u16* __restrict__ outp) {
  const int N = 512;
  __shared__ __align__(16) char smem[81920];
  u16* Sg = (u16*)smem;                 // A buf i @ i*8192 (u16); B buf j @ 24576 + j*8192
  float* Cs = (float*)smem;             // epilogue alias [128][128] f32 (64 KB)

  const int tid = threadIdx.x;
  const int wave = tid >> 6, lane = tid & 63;
  const int wr = (wave >> 1) * 64, wc = (wave & 1) * 64;
  const int lrow = lane & 15, lk = lane >> 4;

  const int nwg = gridDim.x;
  const int wg = (blockIdx.x & 7) * (nwg >> 3) + (blockIdx.x >> 3);
  const int bx = wg % NX, by = wg / NX;
  const size_t m0 = (size_t)by * 128, n0 = (size_t)bx * 128;

  f32x4 acc[4][4] = {};

  const int srow = lane >> 3;
  const int sslot = ((lane & 7) ^ ((lane >> 3) & 7)) * 8;
  auto SA = [&](int buf, int k0) {
#pragma unroll
    for (int c = 0; c < 4; ++c) {
      const int seg = c * 4 + wave;
      llds16(Sg + buf * 8192 + seg * 512,
             A + (m0 + seg * 8 + srow) * (size_t)K + (k0 + sslot));
    }
  };
  auto SB = [&](int buf, int k0) {
#pragma unroll
    for (int c = 0; c < 4; ++c) {
      const int seg = c * 4 + wave;
      llds16(Sg + 24576 + buf * 8192 + seg * 512,
             Bw + (n0 + seg * 8 + srow) * (size_t)K + (k0 + sslot));
    }
  };

  const int NT = K >> 6;   // 32
  SB(0, 0); SA(0, 0); SA(1, 64);

  for (int t = 0; t < NT; ++t) {
    if (t + 1 < NT) SB((t + 1) & 1, (t + 1) << 6);
    if (t + 2 < NT) SA((t + 2) % 3, (t + 2) << 6);
    // ledger (4 loads per SA/SB per wave): steady remaining after wait =
    // SA_{t+1}, SB_{t+1}, SA_{t+2} = 12
    if (t < NT - 2)       WAITV(12);
    else if (t == NT - 2) WAITV(8);
    else                  WAITV(0);
    BAR();

    const u16* Ab = Sg + (t % 3) * 8192;
    const u16* Bb = Sg + 24576 + (t & 1) * 8192;
#pragma unroll
    for (int ks = 0; ks < 2; ++ks) {
      bf16x8 af[4], bfr[4];
#pragma unroll
      for (int m = 0; m < 4; ++m)
        af[m] = *(const bf16x8*)&Ab[(wr + m * 16 + lrow) * 64 +
                                    ((unsigned)((ks * 4 + lk) ^ (lane & 7))) * 8];
#pragma unroll
      for (int n = 0; n < 4; ++n)
        bfr[n] = *(const bf16x8*)&Bb[(wc + n * 16 + lrow) * 64 +
                                     ((unsigned)((ks * 4 + lk) ^ (lane & 7))) * 8];
      __builtin_amdgcn_s_setprio(1);
#pragma unroll
      for (int m = 0; m < 4; ++m)
#pragma unroll
        for (int n = 0; n < 4; ++n)
          acc[m][n] = __builtin_amdgcn_mfma_f32_16x16x32_bf16(af[m], bfr[n],
                                                              acc[m][n], 0, 0, 0);
      __builtin_amdgcn_s_setprio(0);
    }
    LGKM0;
    BAR();
  }

  // epilogue: +bias, relu, LDS-transpose (rotated), coalesced bf16 store
#pragma unroll
  for (int n = 0; n < 4; ++n) {
    const int c = wc + n * 16 + lrow;
    const float bv = bias[n0 + c];
#pragma unroll
    for (int m = 0; m < 4; ++m) {
#pragma unroll
      for (int r = 0; r < 4; ++r) {
        const int row = wr + m * 16 + lk * 4 + r;
        Cs[row * 128 + ((c + ((row >> 2) << 3)) & 127)] = acc[m][n][r] + bv;
      }
    }
  }
  LGKM0;
  BAR();

#pragma unroll
  for (int j = 0; j < 8; ++j) {
    const int flat = tid * 8 + j * 2048;
    const int row = flat >> 7, c = flat & 127;
    const int cp = (c + ((row >> 2) << 3)) & 127;
    const f32x4 c0 = *(const f32x4*)&Cs[row * 128 + cp];
    const f32x4 c1 = *(const f32x4*)&Cs[row * 128 + cp + 4];
    union { u16 us[8]; uint4 u; } p;
    p.us[0] = f2bf(fmaxf(c0[0], 0.0f)); p.us[1] = f2bf(fmaxf(c0[1], 0.0f));
    p.us[2] = f2bf(fmaxf(c0[2], 0.0f)); p.us[3] = f2bf(fmaxf(c0[3], 0.0f));
    p.us[4] = f2bf(fmaxf(c1[0], 0.0f)); p.us[5] = f2bf(fmaxf(c1[1], 0.0f));
    p.us[6] = f2bf(fmaxf(c1[2], 0.0f)); p.us[7] = f2bf(fmaxf(c1[3], 0.0f));
    *(uint4*)&outp[(m0 + row) * (size_t)N + n0 + c] = p.u;
  }
}

// ---- gemm2: out = h2*uwb^T + up_b + resid; K=512, unrolled.
// A (h2) triple-buffered depth-2; B (uwb) double-buffered; resid x-loads
// paced 2/iter into the counted schedule.
// Sequence: SB0 SA0 SA1 | t0: SB1 SA2 R0 R1 | t1..5: SB SA R R | t6: SB7 R12 R13 | t7: R14 R15
// Waits (per-wave ledger): t0=14, t1..5=16, t6=12, t7=4.
__global__ __launch_bounds__(256) void gemm2(
    const u16* __restrict__ A, const u16* __restrict__ Bw,
    int M, const float* __restrict__ bias,
    const float* __restrict__ resid, float* __restrict__ outp) {
  const int K = 512, N = 2048;
  __shared__ __align__(16) char smem[81920];
  u16* Sg = (u16*)smem;                 // A buf i @ i*8192; B buf j @ 24576 + j*8192
  float* Cs = (float*)smem;

  const int tid = threadIdx.x;
  const int wave = tid >> 6, lane = tid & 63;
  const int wr = (wave >> 1) * 64, wc = (wave & 1) * 64;
  const int lrow = lane & 15, lk = lane >> 4;

  const int nwg = gridDim.x;            // 2048, %8==0
  const int wg = (blockIdx.x & 7) * (nwg >> 3) + (blockIdx.x >> 3);
  const int bx = wg & 15, by = wg >> 4; // NX=16
  const size_t m0 = (size_t)by * 128, n0 = (size_t)bx * 128;

  f32x4 acc[4][4] = {};

  const int srow = lane >> 3;
  const int sslot = ((lane & 7) ^ ((lane >> 3) & 7)) * 8;
  auto SA = [&](int buf, int k0) {
#pragma unroll
    for (int c = 0; c < 4; ++c) {
      const int seg = c * 4 + wave;
      llds16(Sg + buf * 8192 + seg * 512,
             A + (m0 + seg * 8 + srow) * (size_t)K + (k0 + sslot));
    }
  };
  auto SB = [&](int buf, int k0) {
#pragma unroll
    for (int c = 0; c < 4; ++c) {
      const int seg = c * 4 + wave;
      llds16(Sg + 24576 + buf * 8192 + seg * 512,
             Bw + (n0 + seg * 8 + srow) * (size_t)K + (k0 + sslot));
    }
  };

  f32x4 rsd[16];
  auto RSD = [&](int j) {
    const int flat = tid * 4 + j * 1024;
    const int row = flat >> 7, c = flat & 127;
    rsd[j] = *(const f32x4*)&resid[(m0 + row) * (size_t)N + n0 + c];
  };

  SB(0, 0); SA(0, 0); SA(1, 64);

#pragma unroll
  for (int t = 0; t < 8; ++t) {
    if (t + 1 < 8) SB((t + 1) & 1, (t + 1) * 64);
    if (t + 2 < 8) SA((t + 2) % 3, (t + 2) * 64);
    if (t < 7) { RSD(2 * t); RSD(2 * t + 1); }
    else       { RSD(14); RSD(15); }
    if (t == 0)      WAITV(14);
    else if (t <= 5) WAITV(16);
    else if (t == 6) WAITV(12);
    else             WAITV(4);   // only R12..R15 (register loads) left in flight
    BAR();

    const u16* Ab = Sg + (t % 3) * 8192;
    const u16* Bb = Sg + 24576 + (t & 1) * 8192;
#pragma unroll
    for (int ks = 0; ks < 2; ++ks) {
      bf16x8 af[4], bfr[4];
#pragma unroll
      for (int m = 0; m < 4; ++m)
        af[m] = *(const bf16x8*)&Ab[(wr + m * 16 + lrow) * 64 +
                                    ((unsigned)((ks * 4 + lk) ^ (lane & 7))) * 8];
#pragma unroll
      for (int n = 0; n < 4; ++n)
        bfr[n] = *(const bf16x8*)&Bb[(wc + n * 16 + lrow) * 64 +
                                     ((unsigned)((ks * 4 + lk) ^ (lane & 7))) * 8];
      __builtin_amdgcn_s_setprio(1);
#pragma unroll
      for (int m = 0; m < 4; ++m)
#pragma unroll
        for (int n = 0; n < 4; ++n)
          acc[m][n] = __builtin_amdgcn_mfma_f32_16x16x32_bf16(af[m], bfr[n],
                                                              acc[m][n], 0, 0, 0);
      __builtin_amdgcn_s_setprio(0);
    }
    LGKM0;
    BAR();
  }

  // epilogue: bias into Cs (rotated), transpose-read, add resid, f32 store
  // (compiler inserts its own vmcnt waits before rsd[12..15] use)
#pragma unroll
  for (int n = 0; n < 4; ++n) {
    const int c = wc + n * 16 + lrow;
    const float bv = bias[n0 + c];
#pragma unroll
    for (int m = 0; m < 4; ++m) {
#pragma unroll
      for (int r = 0; r < 4; ++r) {
        const int row = wr + m * 16 + lk * 4 + r;
        Cs[row * 128 + ((c + ((row >> 2) << 3)) & 127)] = acc[m][n][r] + bv;
      }
    }
  }
  LGKM0;
  BAR();

#pragma unroll
  for (int j = 0; j < 16; ++j) {
    const int flat = tid * 4 + j * 1024;
    const int row = flat >> 7, c = flat & 127;
    const f32x4 cc = *(const f32x4*)&Cs[row * 128 + ((c + ((row >> 2) << 3)) & 127)];
    f32x4 o;
    o[0] = cc[0] + rsd[j][0]; o[1] = cc[1] + rsd[j][1];
    o[2] = cc[2] + rsd[j][2]; o[3] = cc[3] + rsd[j][3];
    *(f32x4*)&outp[(m0 + row) * (size_t)N + n0 + c] = o;
  }
}

extern "C" void kernel_launch(void* const* d_in, const int* in_sizes, int n_in,
                              void* d_out, int out_size, void* d_ws, size_t ws_size,
                              hipStream_t stream) {
  const float* x         = (const float*)d_in[0];
  const float* down_w    = (const float*)d_in[1];
  const float* down_b    = (const float*)d_in[2];
  const float* up_w      = (const float*)d_in[3];
  const float* up_b      = (const float*)d_in[4];
  const float* ln_g      = (const float*)d_in[5];
  const float* ln_b      = (const float*)d_in[6];
  const float* down_loga = (const float*)d_in[7];
  const float* up_loga   = (const float*)d_in[8];
  const int*   lang      = (const int*)d_in[9];

  const int D = 2048, BNK = 512;
  const int M = in_sizes[0] / D;  // 16384

  char* ws = (char*)d_ws;
  u16* h1  = (u16*)ws;                                   // [M][D] bf16
  u16* h2  = (u16*)(ws + (size_t)M * D * 2);             // [M][BNK] bf16
  u16* dwb = (u16*)(ws + (size_t)M * D * 2 + (size_t)M * BNK * 2);  // [BNK][D]
  u16* uwb = dwb + (size_t)BNK * D;                      // [D][BNK]

  prep_weights<<<(BNK * D) / 256, 256, 0, stream>>>(down_w, up_w, down_loga,
                                                    up_loga, lang, dwb, uwb);
  ln_kernel<<<M, 256, 0, stream>>>(x, ln_g, ln_b, h1);
  gemm1<<<(M / 128) * (BNK / 128), 256, 0, stream>>>(h1, dwb, M, D, BNK / 128,
                                                     down_b, h2);
  gemm2<<<(M / 128) * (D / 128), 256, 0, stream>>>(h2, uwb, M, up_b, x,
                                                   (float*)d_out);
}